// Round 8
// baseline (99.737 us; speedup 1.0000x reference)
//
#include <hip/hip_runtime.h>
#include <hip/hip_bf16.h>

typedef __bf16 bf16;
typedef __bf16 bf16x8 __attribute__((ext_vector_type(8)));
typedef float f32x4 __attribute__((ext_vector_type(4)));
typedef float f32x16 __attribute__((ext_vector_type(16)));
typedef unsigned int u32x4 __attribute__((ext_vector_type(4)));

#define EXP2(x) __builtin_amdgcn_exp2f(x)

static __device__ __forceinline__ f32x4 mfma16(bf16x8 a, bf16x8 b, f32x4 c) {
    return __builtin_amdgcn_mfma_f32_16x16x32_bf16(a, b, c, 0, 0, 0);
}
static __device__ __forceinline__ f32x16 mfma32(bf16x8 a, bf16x8 b, f32x16 c) {
    return __builtin_amdgcn_mfma_f32_32x32x16_bf16(a, b, c, 0, 0, 0);
}
static __device__ __forceinline__ unsigned cvt_pk(float lo, float hi) {
    unsigned r;
    asm("v_cvt_pk_bf16_f32 %0, %1, %2" : "=v"(r) : "v"(lo), "v"(hi));
    return r;
}
static __device__ __forceinline__ void perm32swap(unsigned &a, unsigned &b) {
    asm("v_permlane32_swap_b32 %0, %1" : "+v"(a), "+v"(b));
}

// ---------------- Kernel 1: weight convert ---------------------------------------------
// wqkv: bf16 copy with softmax scale*log2e folded into Q rows.
// wproj: packed into 32x32-MFMA A-fragment order Wp[ot][kc][lane][8]:
//        element (o = ot*32+l31, c = kc*16 + hi*8 + j) at ((ot*16+kc)*64 + hi*32+l31)*8 + j.
__global__ __launch_bounds__(256) void prep_w_kernel(const float* __restrict__ qkv_w,
                                                     const float* __restrict__ proj_w,
                                                     bf16* __restrict__ wqkv,
                                                     bf16* __restrict__ Wp) {
    int idx = blockIdx.x * 256 + threadIdx.x;
    const float QSCALE = 0.17677669529663689f * 1.4426950408889634f; // hd^-0.5 * log2(e)
    if (idx < 768 * 256) {
        float v = qkv_w[idx];
        if (idx < 256 * 256) v *= QSCALE;   // rows o<256 are the Q projection
        wqkv[idx] = (bf16)v;
    } else {
        int j = idx - 768 * 256;
        int o = j >> 8, c = j & 255;
        int ot = o >> 5, l31 = o & 31;
        int kc = c >> 4, hi = (c >> 3) & 1, jj = c & 7;
        Wp[(size_t)(((ot * 16 + kc) * 64 + hi * 32 + l31) * 8 + jj)] = (bf16)proj_w[j];
    }
}

// ---------------- Kernel 2: x [2][256][4096] f32 -> xT [2][4096][256] bf16 ------------
__global__ __launch_bounds__(256) void transpose_x_kernel(const float* __restrict__ x,
                                                          bf16* __restrict__ xT) {
    __shared__ float tile[64][68];
    int b = blockIdx.z, cb = blockIdx.y * 64, nb = blockIdx.x * 64;
    int t = threadIdx.x;
    int j = t & 15, rc = t >> 4;
    const float* src = x + ((size_t)b * 256 + cb) * 4096 + nb;
#pragma unroll
    for (int i = 0; i < 4; i++) {
        f32x4 v = *(const f32x4*)(src + (size_t)(rc + i * 16) * 4096 + j * 4);
        *(f32x4*)&tile[rc + i * 16][j * 4] = v;
    }
    __syncthreads();
    int n = t >> 2;
    bf16* dst = xT + ((size_t)b * 4096 + nb + n) * 256 + cb;
#pragma unroll
    for (int i = 0; i < 2; i++) {
        int c0 = ((t & 3) + i * 4) * 8;
        bf16x8 v;
#pragma unroll
        for (int jj = 0; jj < 8; jj++) v[jj] = (bf16)tile[c0 + jj][n];
        *(bf16x8*)(dst + c0) = v;
    }
}

// ---------------- Kernel 3: QKV GEMM (unchanged from R7) ------------------------------
__global__ __launch_bounds__(256) void qkv_gemm_kernel(const bf16* __restrict__ xT,
                                                       const bf16* __restrict__ w,
                                                       bf16* __restrict__ Q,
                                                       bf16* __restrict__ Kp,
                                                       bf16* __restrict__ Vp) {
    int b = blockIdx.z;
    int nb = blockIdx.x * 64, ob = blockIdx.y * 128;
    int t = threadIdx.x, wid = t >> 6, lane = t & 63;
    int l15 = lane & 15, g = lane >> 4;
    int wr = wid >> 1, wc = wid & 1;
    const bf16* xrow = xT + ((size_t)b * 4096 + nb + wr * 32 + l15) * 256 + g * 8;
    const bf16* wrow = w + (size_t)(ob + wc * 64 + l15) * 256 + g * 8;
    f32x4 acc[2][4] = {};
    for (int k0 = 0; k0 < 256; k0 += 32) {
        bf16x8 a[2], bb[4];
#pragma unroll
        for (int rt = 0; rt < 2; rt++) a[rt] = *(const bf16x8*)(xrow + rt * 16 * 256 + k0);
#pragma unroll
        for (int cg = 0; cg < 4; cg++) bb[cg] = *(const bf16x8*)(wrow + cg * 16 * 256 + k0);
#pragma unroll
        for (int rt = 0; rt < 2; rt++)
#pragma unroll
            for (int cg = 0; cg < 4; cg++)
                acc[rt][cg] = mfma16(a[rt], bb[cg], acc[rt][cg]);
    }
#pragma unroll
    for (int rt = 0; rt < 2; rt++) {
#pragma unroll
        for (int cg = 0; cg < 4; cg++) {
            int o = ob + wc * 64 + cg * 16 + l15;
            int tsel = o >> 8;           // 0=Q 1=K 2=V
            int h = (o >> 5) & 7;
            int d = o & 31;
            int n0 = nb + wr * 32 + rt * 16 + g * 4;
            size_t bhbase = ((size_t)b * 8 + h) * 131072;
            if (tsel == 0) {
#pragma unroll
                for (int i = 0; i < 4; i++)
                    Q[(((size_t)b * 8 + h) * 4096 + n0 + i) * 32 + d] = (bf16)acc[rt][cg][i];
            } else if (tsel == 1) {
                int kt = n0 >> 5;
                int which = d >> 4, hi2 = (d >> 3) & 1, j = d & 7;
                size_t base = bhbase + (size_t)(((kt * 2 + which) * 64 + hi2 * 32) * 8 + j);
#pragma unroll
                for (int i = 0; i < 4; i++) {
                    int r5 = (n0 + i) & 31;
                    Kp[base + r5 * 8] = (bf16)acc[rt][cg][i];
                }
            } else {
                int kt = n0 >> 5, kk0 = n0 & 31;
                int which = kk0 >> 4, hi2 = (kk0 >> 3) & 1, j0 = kk0 & 7;
                unsigned p0 = cvt_pk(acc[rt][cg][0], acc[rt][cg][1]);
                unsigned p1 = cvt_pk(acc[rt][cg][2], acc[rt][cg][3]);
                uint2 wv; wv.x = p0; wv.y = p1;
                *(uint2*)(Vp + bhbase + (size_t)(((kt * 2 + which) * 64 + hi2 * 32 + d) * 8 + j0)) = wv;
            }
        }
    }
}

// ---------------- Kernel 4: flash attention, 64 q/wave, k-split 4 ---------------------
// 1-D grid 1024 blocks (XCD-swizzled: bh = (w&7)+8*((w>>3)&1), qblk = w>>4).
// 256 thr = 4 waves, wave = k-quarter z. Each wave: 64 q-rows (2 groups of 32),
// quarter k-range, KVBLK=32 -> each K/V fragment load serves TWO q-groups
// (halves L1 traffic per S-element vs R7). Fixed-base softmax; partials
// combined via LDS; output written DIRECTLY in proj B-fragment packed order:
//   attP element (b,n,c) at (((b*128 + n>>5)*16 + c>>4)*64 + ((c>>3)&1)*32 + (n&31))*8 + (c&7)
#define PACK(stv, B, OUT) {                                  \
    unsigned _x01 = cvt_pk(stv[B + 0], stv[B + 1]);          \
    unsigned _x23 = cvt_pk(stv[B + 2], stv[B + 3]);          \
    unsigned _y01 = cvt_pk(stv[B + 4], stv[B + 5]);          \
    unsigned _y23 = cvt_pk(stv[B + 6], stv[B + 7]);          \
    perm32swap(_x01, _y01);                                  \
    perm32swap(_x23, _y23);                                  \
    u32x4 _w = {_x01, _x23, _y01, _y23};                     \
    OUT = __builtin_bit_cast(bf16x8, _w); }

// process one q-group: exp, sum, pack, PV
#define PROC(ST, OACC, LP) {                                 \
    _Pragma("unroll")                                        \
    for (int r = 0; r < 16; r++) ST[r] = EXP2(ST[r]);        \
    float _s0 = 0.f, _s1 = 0.f;                              \
    _Pragma("unroll")                                        \
    for (int r = 0; r < 8; r++) { _s0 += ST[r]; _s1 += ST[r + 8]; } \
    LP += _s0 + _s1;                                         \
    bf16x8 _pb0, _pb1;                                       \
    PACK(ST, 0, _pb0);                                       \
    PACK(ST, 8, _pb1);                                       \
    __builtin_amdgcn_s_setprio(1);                           \
    OACC = mfma32(vf0, _pb0, OACC);                          \
    OACC = mfma32(vf1, _pb1, OACC);                          \
    __builtin_amdgcn_s_setprio(0); }

__global__ __launch_bounds__(256) void attn_kernel(const bf16* __restrict__ Q,
                                                   const bf16* __restrict__ Kp,
                                                   const bf16* __restrict__ Vp,
                                                   bf16* __restrict__ attP) {
    __shared__ __align__(16) float ldsO[3][2][64][20];   // ~30.7 KB
    __shared__ float ldsL[3][2][32];

    const int w = blockIdx.x;
    const int bh = (w & 7) + 8 * ((w >> 3) & 1);
    const int qblk = w >> 4;                       // 0..63 (64 q each)
    const int t = threadIdx.x;
    const int z = t >> 6, lane = t & 63;           // z: k-quarter
    const int l31 = lane & 31, hi = lane >> 5;
    const int q0 = qblk * 64;

    const bf16* __restrict__ Qb = Q + (size_t)bh * 4096 * 32;
    const bf16* kptr = Kp + (size_t)bh * 131072 + (size_t)z * 32768 + lane * 8;
    const bf16* vptr = Vp + (size_t)bh * 131072 + (size_t)z * 32768 + lane * 8;

    // Q B-frags for both q-groups (col = q = l31, elems d = ks*16 + hi*8 + j)
    bf16x8 qfA0 = *(const bf16x8*)(Qb + (size_t)(q0 + l31) * 32 + hi * 8);
    bf16x8 qfA1 = *(const bf16x8*)(Qb + (size_t)(q0 + l31) * 32 + 16 + hi * 8);
    bf16x8 qfB0 = *(const bf16x8*)(Qb + (size_t)(q0 + 32 + l31) * 32 + hi * 8);
    bf16x8 qfB1 = *(const bf16x8*)(Qb + (size_t)(q0 + 32 + l31) * 32 + 16 + hi * 8);

    const f32x16 ZERO16 = {};
    f32x16 oA = {}, oB = {};
    float lA = 0.f, lB = 0.f;

    for (int it = 0; it < 32; ++it) {
        bf16x8 kf0 = *(const bf16x8*)(kptr);
        bf16x8 kf1 = *(const bf16x8*)(kptr + 512);
        bf16x8 vf0 = *(const bf16x8*)(vptr);
        bf16x8 vf1 = *(const bf16x8*)(vptr + 512);
        kptr += 1024; vptr += 1024;

        // group A
        f32x16 st = mfma32(kf0, qfA0, ZERO16);
        st = mfma32(kf1, qfA1, st);
        PROC(st, oA, lA);
        // group B (kf still live)
        st = mfma32(kf0, qfB0, ZERO16);
        st = mfma32(kf1, qfB1, st);
        PROC(st, oB, lB);
    }

    lA += __shfl_xor(lA, 32);
    lB += __shfl_xor(lB, 32);

    // ---- combine 4 k-quarter partials via LDS, write attP packed ----
    if (z != 0) {
#pragma unroll
        for (int g = 0; g < 4; g++) {
            *(f32x4*)&ldsO[z - 1][0][lane][4 * g] =
                f32x4{oA[4 * g + 0], oA[4 * g + 1], oA[4 * g + 2], oA[4 * g + 3]};
            *(f32x4*)&ldsO[z - 1][1][lane][4 * g] =
                f32x4{oB[4 * g + 0], oB[4 * g + 1], oB[4 * g + 2], oB[4 * g + 3]};
        }
        if (hi == 0) { ldsL[z - 1][0][l31] = lA; ldsL[z - 1][1][l31] = lB; }
    }
    __syncthreads();
    if (z == 0) {
        const int b = bh >> 3, h = bh & 7;
#pragma unroll
        for (int qg = 0; qg < 2; qg++) {
            const f32x16& oo = qg ? oB : oA;
            float lsum = (qg ? lB : lA) + ldsL[0][qg][l31] + ldsL[1][qg][l31] + ldsL[2][qg][l31];
            float inv = __builtin_amdgcn_rcpf(lsum);
            int nt = qblk * 2 + qg;
            size_t base = (((size_t)b * 128 + nt) * 16) * 512;   // *64*8
#pragma unroll
            for (int g = 0; g < 4; g++) {
                f32x4 p0 = *(const f32x4*)&ldsO[0][qg][lane][4 * g];
                f32x4 p1 = *(const f32x4*)&ldsO[1][qg][lane][4 * g];
                f32x4 p2 = *(const f32x4*)&ldsO[2][qg][lane][4 * g];
                float e0 = (oo[4 * g + 0] + p0[0] + p1[0] + p2[0]) * inv;
                float e1 = (oo[4 * g + 1] + p0[1] + p1[1] + p2[1]) * inv;
                float e2 = (oo[4 * g + 2] + p0[2] + p1[2] + p2[2]) * inv;
                float e3 = (oo[4 * g + 3] + p0[3] + p1[3] + p2[3]) * inv;
                // element d = 8g + 4hi + m; c = h*32 + d
                size_t addr = base + (size_t)(((h * 2 + (g >> 1)) * 64 + (g & 1) * 32 + l31) * 8 + 4 * hi);
                uint2 wv;
                wv.x = cvt_pk(e0, e1);
                wv.y = cvt_pk(e2, e3);
                *(uint2*)(attP + addr) = wv;
            }
        }
    }
}

// ---------------- Kernel 5: proj GEMM, fragment-packed --------------------------------
// out[b][o][n] = wproj[o][c] * att[c][n] + bias[o].  D = A(Wp) x B(attP), 32x32x16.
// grid 512 blocks x 256 thr; block = (b, nt, oh); wave wid -> ot = oh*4+wid.
__global__ __launch_bounds__(256) void proj_gemm_kernel(const bf16* __restrict__ attP,
                                                        const bf16* __restrict__ Wp,
                                                        const float* __restrict__ bias,
                                                        float* __restrict__ out) {
    int bid = blockIdx.x;
    int b = bid >> 8, rest = bid & 255;
    int nt = rest >> 1, oh = rest & 1;
    int t = threadIdx.x, wid = t >> 6, lane = t & 63;
    int l31 = lane & 31, hi = lane >> 5;
    int ot = oh * 4 + wid;

    const bf16* ap = Wp + (size_t)(ot * 16) * 512 + lane * 8;
    const bf16* bp = attP + (((size_t)b * 128 + nt) * 16) * 512 + lane * 8;
    f32x16 acc = {};
#pragma unroll
    for (int kc = 0; kc < 16; kc++) {
        bf16x8 af = *(const bf16x8*)(ap + kc * 512);
        bf16x8 bf = *(const bf16x8*)(bp + kc * 512);
        acc = mfma32(af, bf, acc);
    }
    // D: row(o-local) = (r&3)+8*(r>>2)+4*hi, col(n-local) = l31
    float* obase = out + ((size_t)b * 256 + ot * 32) * 4096 + nt * 32 + l31;
#pragma unroll
    for (int r = 0; r < 16; r++) {
        int row = (r & 3) + 8 * (r >> 2) + 4 * hi;
        obase[(size_t)row * 4096] = acc[r] + bias[ot * 32 + row];
    }
}

// ---------------- launch --------------------------------------------------------------
extern "C" void kernel_launch(void* const* d_in, const int* in_sizes, int n_in,
                              void* d_out, int out_size, void* d_ws, size_t ws_size,
                              hipStream_t stream) {
    const float* x      = (const float*)d_in[0];
    const float* qkv_w  = (const float*)d_in[1];
    const float* proj_w = (const float*)d_in[2];
    const float* proj_b = (const float*)d_in[3];
    float* out = (float*)d_out;

    char* ws = (char*)d_ws;
    bf16* xT    = (bf16*)(ws);                    // 4,194,304 B
    bf16* wqkv  = (bf16*)(ws + 4194304);          //   393,216 B
    bf16* Wp    = (bf16*)(ws + 4587520);          //   131,072 B (packed wproj)
    bf16* Qb    = (bf16*)(ws + 4718592);          // 4,194,304 B
    bf16* Kp    = (bf16*)(ws + 8912896);          // 4,194,304 B (fragment-packed)
    bf16* Vp    = (bf16*)(ws + 13107200);         // 4,194,304 B (fragment-packed)
    bf16* attP  = (bf16*)(ws + 17301504);         // 4,194,304 B (fragment-packed) -> 21,495,808

    prep_w_kernel<<<1024, 256, 0, stream>>>(qkv_w, proj_w, wqkv, Wp);
    transpose_x_kernel<<<dim3(64, 4, 2), 256, 0, stream>>>(x, xT);
    qkv_gemm_kernel<<<dim3(64, 6, 2), 256, 0, stream>>>(xT, wqkv, Qb, Kp, Vp);
    attn_kernel<<<1024, 256, 0, stream>>>(Qb, Kp, Vp, attP);
    proj_gemm_kernel<<<512, 256, 0, stream>>>(attP, Wp, proj_b, out);
}

// Round 9
// 90.574 us; speedup vs baseline: 1.1012x; 1.1012x over previous
//
#include <hip/hip_runtime.h>
#include <hip/hip_bf16.h>

typedef __bf16 bf16;
typedef __bf16 bf16x8 __attribute__((ext_vector_type(8)));
typedef float f32x4 __attribute__((ext_vector_type(4)));
typedef float f32x16 __attribute__((ext_vector_type(16)));
typedef unsigned int u32x4 __attribute__((ext_vector_type(4)));

#define EXP2(x) __builtin_amdgcn_exp2f(x)

static __device__ __forceinline__ f32x4 mfma16(bf16x8 a, bf16x8 b, f32x4 c) {
    return __builtin_amdgcn_mfma_f32_16x16x32_bf16(a, b, c, 0, 0, 0);
}
static __device__ __forceinline__ f32x16 mfma32(bf16x8 a, bf16x8 b, f32x16 c) {
    return __builtin_amdgcn_mfma_f32_32x32x16_bf16(a, b, c, 0, 0, 0);
}
static __device__ __forceinline__ unsigned cvt_pk(float lo, float hi) {
    unsigned r;
    asm("v_cvt_pk_bf16_f32 %0, %1, %2" : "=v"(r) : "v"(lo), "v"(hi));
    return r;
}
static __device__ __forceinline__ void perm32swap(unsigned &a, unsigned &b) {
    asm("v_permlane32_swap_b32 %0, %1" : "+v"(a), "+v"(b));
}

// ---------------- Kernel 1: weight convert ---------------------------------------------
// wqkv: bf16 copy with softmax scale*log2e folded into Q rows.
// wproj packed into 32x32-MFMA A-fragment order Wp[ot][kc][lane][8].
__global__ __launch_bounds__(256) void prep_w_kernel(const float* __restrict__ qkv_w,
                                                     const float* __restrict__ proj_w,
                                                     bf16* __restrict__ wqkv,
                                                     bf16* __restrict__ Wp) {
    int idx = blockIdx.x * 256 + threadIdx.x;
    const float QSCALE = 0.17677669529663689f * 1.4426950408889634f; // hd^-0.5 * log2(e)
    if (idx < 768 * 256) {
        float v = qkv_w[idx];
        if (idx < 256 * 256) v *= QSCALE;
        wqkv[idx] = (bf16)v;
    } else {
        int j = idx - 768 * 256;
        int o = j >> 8, c = j & 255;
        int ot = o >> 5, l31 = o & 31;
        int kc = c >> 4, hi = (c >> 3) & 1, jj = c & 7;
        Wp[(size_t)(((ot * 16 + kc) * 64 + hi * 32 + l31) * 8 + jj)] = (bf16)proj_w[j];
    }
}

// ---------------- Kernel 2: x [2][256][4096] f32 -> xT [2][4096][256] bf16 ------------
__global__ __launch_bounds__(256) void transpose_x_kernel(const float* __restrict__ x,
                                                          bf16* __restrict__ xT) {
    __shared__ float tile[64][68];
    int b = blockIdx.z, cb = blockIdx.y * 64, nb = blockIdx.x * 64;
    int t = threadIdx.x;
    int j = t & 15, rc = t >> 4;
    const float* src = x + ((size_t)b * 256 + cb) * 4096 + nb;
#pragma unroll
    for (int i = 0; i < 4; i++) {
        f32x4 v = *(const f32x4*)(src + (size_t)(rc + i * 16) * 4096 + j * 4);
        *(f32x4*)&tile[rc + i * 16][j * 4] = v;
    }
    __syncthreads();
    int n = t >> 2;
    bf16* dst = xT + ((size_t)b * 4096 + nb + n) * 256 + cb;
#pragma unroll
    for (int i = 0; i < 2; i++) {
        int c0 = ((t & 3) + i * 4) * 8;
        bf16x8 v;
#pragma unroll
        for (int jj = 0; jj < 8; jj++) v[jj] = (bf16)tile[c0 + jj][n];
        *(bf16x8*)(dst + c0) = v;
    }
}

// ---------------- Kernel 3: QKV GEMM (unchanged) --------------------------------------
__global__ __launch_bounds__(256) void qkv_gemm_kernel(const bf16* __restrict__ xT,
                                                       const bf16* __restrict__ w,
                                                       bf16* __restrict__ Q,
                                                       bf16* __restrict__ Kp,
                                                       bf16* __restrict__ Vp) {
    int b = blockIdx.z;
    int nb = blockIdx.x * 64, ob = blockIdx.y * 128;
    int t = threadIdx.x, wid = t >> 6, lane = t & 63;
    int l15 = lane & 15, g = lane >> 4;
    int wr = wid >> 1, wc = wid & 1;
    const bf16* xrow = xT + ((size_t)b * 4096 + nb + wr * 32 + l15) * 256 + g * 8;
    const bf16* wrow = w + (size_t)(ob + wc * 64 + l15) * 256 + g * 8;
    f32x4 acc[2][4] = {};
    for (int k0 = 0; k0 < 256; k0 += 32) {
        bf16x8 a[2], bb[4];
#pragma unroll
        for (int rt = 0; rt < 2; rt++) a[rt] = *(const bf16x8*)(xrow + rt * 16 * 256 + k0);
#pragma unroll
        for (int cg = 0; cg < 4; cg++) bb[cg] = *(const bf16x8*)(wrow + cg * 16 * 256 + k0);
#pragma unroll
        for (int rt = 0; rt < 2; rt++)
#pragma unroll
            for (int cg = 0; cg < 4; cg++)
                acc[rt][cg] = mfma16(a[rt], bb[cg], acc[rt][cg]);
    }
#pragma unroll
    for (int rt = 0; rt < 2; rt++) {
#pragma unroll
        for (int cg = 0; cg < 4; cg++) {
            int o = ob + wc * 64 + cg * 16 + l15;
            int tsel = o >> 8;           // 0=Q 1=K 2=V
            int h = (o >> 5) & 7;
            int d = o & 31;
            int n0 = nb + wr * 32 + rt * 16 + g * 4;
            size_t bhbase = ((size_t)b * 8 + h) * 131072;
            if (tsel == 0) {
#pragma unroll
                for (int i = 0; i < 4; i++)
                    Q[(((size_t)b * 8 + h) * 4096 + n0 + i) * 32 + d] = (bf16)acc[rt][cg][i];
            } else if (tsel == 1) {
                int kt = n0 >> 5;
                int which = d >> 4, hi2 = (d >> 3) & 1, j = d & 7;
                size_t base = bhbase + (size_t)(((kt * 2 + which) * 64 + hi2 * 32) * 8 + j);
#pragma unroll
                for (int i = 0; i < 4; i++) {
                    int r5 = (n0 + i) & 31;
                    Kp[base + r5 * 8] = (bf16)acc[rt][cg][i];
                }
            } else {
                int kt = n0 >> 5, kk0 = n0 & 31;
                int which = kk0 >> 4, hi2 = (kk0 >> 3) & 1, j0 = kk0 & 7;
                unsigned p0 = cvt_pk(acc[rt][cg][0], acc[rt][cg][1]);
                unsigned p1 = cvt_pk(acc[rt][cg][2], acc[rt][cg][3]);
                uint2 wv; wv.x = p0; wv.y = p1;
                *(uint2*)(Vp + bhbase + (size_t)(((kt * 2 + which) * 64 + hi2 * 32 + d) * 8 + j0)) = wv;
            }
        }
    }
}

// ---------------- Kernel 4: flash attention, decorrelated k-streams -------------------
// Grid 1024 (XCD-swizzled: bh=(w&7)+8*((w>>3)&1), qblk=w>>4 in 0..63).
// 512 thr = 8 waves: zraw = wid>>1 (k-quarter slot), wq = wid&1 (q-subtile).
// DECORRELATION: quarter z = (zraw + qblk) & 3 (blocks sharing bh work different
// quarters at any instant) + start-tile stagger (qblk*11)&31 inside the quarter
// (legal because fixed-base softmax is order-independent). wq pairs keep identical
// k-addresses -> L1 reuse. Output written directly in proj-B-fragment packed order.
#define PACK(stv, B, OUT) {                                  \
    unsigned _x01 = cvt_pk(stv[B + 0], stv[B + 1]);          \
    unsigned _x23 = cvt_pk(stv[B + 2], stv[B + 3]);          \
    unsigned _y01 = cvt_pk(stv[B + 4], stv[B + 5]);          \
    unsigned _y23 = cvt_pk(stv[B + 6], stv[B + 7]);          \
    perm32swap(_x01, _y01);                                  \
    perm32swap(_x23, _y23);                                  \
    u32x4 _w = {_x01, _x23, _y01, _y23};                     \
    OUT = __builtin_bit_cast(bf16x8, _w); }

#define SEG(KP, VP, CNT) {                                   \
    const bf16* _kp = (KP);                                  \
    const bf16* _vp = (VP);                                  \
    for (int _i = 0; _i < (CNT); ++_i) {                     \
        bf16x8 kf0 = *(const bf16x8*)(_kp);                  \
        bf16x8 kf1 = *(const bf16x8*)(_kp + 512);            \
        bf16x8 vf0 = *(const bf16x8*)(_vp);                  \
        bf16x8 vf1 = *(const bf16x8*)(_vp + 512);            \
        _kp += 1024; _vp += 1024;                            \
        f32x16 st = mfma32(kf0, qf0, ZERO16);                \
        st = mfma32(kf1, qf1, st);                           \
        _Pragma("unroll")                                    \
        for (int r = 0; r < 16; r++) st[r] = EXP2(st[r]);    \
        float _s0 = 0.f, _s1 = 0.f;                          \
        _Pragma("unroll")                                    \
        for (int r = 0; r < 8; r++) { _s0 += st[r]; _s1 += st[r + 8]; } \
        lpart += _s0 + _s1;                                  \
        bf16x8 _pb0, _pb1;                                   \
        PACK(st, 0, _pb0);                                   \
        PACK(st, 8, _pb1);                                   \
        __builtin_amdgcn_s_setprio(1);                       \
        o_acc = mfma32(vf0, _pb0, o_acc);                    \
        o_acc = mfma32(vf1, _pb1, o_acc);                    \
        __builtin_amdgcn_s_setprio(0);                       \
    } }

__global__ __launch_bounds__(512, 6) void attn_kernel(const bf16* __restrict__ Q,
                                                      const bf16* __restrict__ Kp,
                                                      const bf16* __restrict__ Vp,
                                                      bf16* __restrict__ attP) {
    __shared__ __align__(16) float ldsO[3][2][64][20];
    __shared__ float ldsL[3][2][32];

    const int w = blockIdx.x;
    const int bh = (w & 7) + 8 * ((w >> 3) & 1);
    const int qblk = w >> 4;                        // 0..63
    const int t = threadIdx.x;
    const int wid = t >> 6, lane = t & 63;
    const int zraw = wid >> 1, wq = wid & 1;
    const int z = (zraw + qblk) & 3;                // rotated k-quarter
    const int l31 = lane & 31, hi = lane >> 5;
    const int q0 = qblk * 64 + wq * 32;

    const bf16* __restrict__ Qb = Q + (size_t)bh * 4096 * 32;
    const bf16* kq = Kp + (size_t)bh * 131072 + (size_t)z * 32768 + lane * 8;
    const bf16* vq = Vp + (size_t)bh * 131072 + (size_t)z * 32768 + lane * 8;

    bf16x8 qf0 = *(const bf16x8*)(Qb + (size_t)(q0 + l31) * 32 + hi * 8);
    bf16x8 qf1 = *(const bf16x8*)(Qb + (size_t)(q0 + l31) * 32 + 16 + hi * 8);

    const f32x16 ZERO16 = {};
    f32x16 o_acc = {};
    float lpart = 0.f;

    const int st0 = (qblk * 11) & 31;               // start tile within quarter
    SEG(kq + (size_t)st0 * 1024, vq + (size_t)st0 * 1024, 32 - st0);
    SEG(kq, vq, st0);

    lpart += __shfl_xor(lpart, 32);

    // ---- combine 4 k-quarter partials via LDS, write attP packed ----
    if (zraw != 0) {
#pragma unroll
        for (int g = 0; g < 4; g++)
            *(f32x4*)&ldsO[zraw - 1][wq][lane][4 * g] =
                f32x4{o_acc[4 * g + 0], o_acc[4 * g + 1], o_acc[4 * g + 2], o_acc[4 * g + 3]};
        if (hi == 0) ldsL[zraw - 1][wq][l31] = lpart;
    }
    __syncthreads();
    if (zraw == 0) {
        const int b = bh >> 3, h = bh & 7;
        float lsum = lpart + ldsL[0][wq][l31] + ldsL[1][wq][l31] + ldsL[2][wq][l31];
        float inv = __builtin_amdgcn_rcpf(lsum);
        int nt = qblk * 2 + wq;
        size_t base = (((size_t)b * 128 + nt) * 16) * 512;
#pragma unroll
        for (int g = 0; g < 4; g++) {
            f32x4 p0 = *(const f32x4*)&ldsO[0][wq][lane][4 * g];
            f32x4 p1 = *(const f32x4*)&ldsO[1][wq][lane][4 * g];
            f32x4 p2 = *(const f32x4*)&ldsO[2][wq][lane][4 * g];
            float e0 = (o_acc[4 * g + 0] + p0[0] + p1[0] + p2[0]) * inv;
            float e1 = (o_acc[4 * g + 1] + p0[1] + p1[1] + p2[1]) * inv;
            float e2 = (o_acc[4 * g + 2] + p0[2] + p1[2] + p2[2]) * inv;
            float e3 = (o_acc[4 * g + 3] + p0[3] + p1[3] + p2[3]) * inv;
            size_t addr = base + (size_t)(((h * 2 + (g >> 1)) * 64 + (g & 1) * 32 + l31) * 8 + 4 * hi);
            uint2 wv;
            wv.x = cvt_pk(e0, e1);
            wv.y = cvt_pk(e2, e3);
            *(uint2*)(attP + addr) = wv;
        }
    }
}

// ---------------- Kernel 5: proj GEMM, fragment-packed (unchanged) --------------------
__global__ __launch_bounds__(256) void proj_gemm_kernel(const bf16* __restrict__ attP,
                                                        const bf16* __restrict__ Wp,
                                                        const float* __restrict__ bias,
                                                        float* __restrict__ out) {
    int bid = blockIdx.x;
    int b = bid >> 8, rest = bid & 255;
    int nt = rest >> 1, oh = rest & 1;
    int t = threadIdx.x, wid = t >> 6, lane = t & 63;
    int l31 = lane & 31, hi = lane >> 5;
    int ot = oh * 4 + wid;

    const bf16* ap = Wp + (size_t)(ot * 16) * 512 + lane * 8;
    const bf16* bp = attP + (((size_t)b * 128 + nt) * 16) * 512 + lane * 8;
    f32x16 acc = {};
#pragma unroll
    for (int kc = 0; kc < 16; kc++) {
        bf16x8 af = *(const bf16x8*)(ap + kc * 512);
        bf16x8 bf = *(const bf16x8*)(bp + kc * 512);
        acc = mfma32(af, bf, acc);
    }
    float* obase = out + ((size_t)b * 256 + ot * 32) * 4096 + nt * 32 + l31;
#pragma unroll
    for (int r = 0; r < 16; r++) {
        int row = (r & 3) + 8 * (r >> 2) + 4 * hi;
        obase[(size_t)row * 4096] = acc[r] + bias[ot * 32 + row];
    }
}

// ---------------- launch --------------------------------------------------------------
extern "C" void kernel_launch(void* const* d_in, const int* in_sizes, int n_in,
                              void* d_out, int out_size, void* d_ws, size_t ws_size,
                              hipStream_t stream) {
    const float* x      = (const float*)d_in[0];
    const float* qkv_w  = (const float*)d_in[1];
    const float* proj_w = (const float*)d_in[2];
    const float* proj_b = (const float*)d_in[3];
    float* out = (float*)d_out;

    char* ws = (char*)d_ws;
    bf16* xT    = (bf16*)(ws);                    // 4,194,304 B
    bf16* wqkv  = (bf16*)(ws + 4194304);          //   393,216 B
    bf16* Wp    = (bf16*)(ws + 4587520);          //   131,072 B (packed wproj)
    bf16* Qb    = (bf16*)(ws + 4718592);          // 4,194,304 B
    bf16* Kp    = (bf16*)(ws + 8912896);          // 4,194,304 B (fragment-packed)
    bf16* Vp    = (bf16*)(ws + 13107200);         // 4,194,304 B (fragment-packed)
    bf16* attP  = (bf16*)(ws + 17301504);         // 4,194,304 B (fragment-packed)

    prep_w_kernel<<<1024, 256, 0, stream>>>(qkv_w, proj_w, wqkv, Wp);
    transpose_x_kernel<<<dim3(64, 4, 2), 256, 0, stream>>>(x, xT);
    qkv_gemm_kernel<<<dim3(64, 6, 2), 256, 0, stream>>>(xT, wqkv, Qb, Kp, Vp);
    attn_kernel<<<1024, 512, 0, stream>>>(Qb, Kp, Vp, attP);
    proj_gemm_kernel<<<512, 256, 0, stream>>>(attP, Wp, proj_b, out);
}